// Round 2
// baseline (462.039 us; speedup 1.0000x reference)
//
#include <hip/hip_runtime.h>

#define NPTS 8192
#define KNNK 16
#define NSLOT 17          // keep 17, fp64-refine drops the worst -> robust 16-set
#define LEAKY 0.1f

typedef short bf16x8 __attribute__((ext_vector_type(8)));
typedef float f32x4  __attribute__((ext_vector_type(4)));

// ---- knn config ----
#define KTH   256              // threads/block (4 waves)
#define QPB   64               // queries per block -> grid 512
#define CHN   32               // chunks (threads) per query
#define GQ    8                // queries per thread
#define JP    (NPTS / 64)      // 128 iters, 2 adjacent candidates per thread/iter
#define BUFCAP 48              // survivor buffer per query

// ---------------------------------------------------------------------------
// R6: occupancy fix. R5 cut VALU ops 1/3 (VALUBusy 63->42%) but dur stayed
// 224us => latency-bound at 2 waves/SIMD (LDS 145KB = 1 block/CU). Candidate
// SoA (96KB) moves from LDS to an L2-resident global scratch written by a
// tiny prep kernel; knn LDS drops to ~25KB (survivor buffers only) and
// blocks shrink to 256thr/QPB=64 so occupancy is VGPR-capped (4-5 waves/SIMD,
// 2-2.5x). Candidate reads stay coalesced dwordx2 streams (L2-fed).
// Distance math / rank-17 threshold / survivor buffer / fp64 refine unchanged.
// ---------------------------------------------------------------------------

__global__ __launch_bounds__(256) void prep_kernel(
    const float* __restrict__ pc1, const float* __restrict__ pc2,
    float* __restrict__ soa)
{
    const int i = blockIdx.x * blockDim.x + threadIdx.x;   // 0..32767
    const int set = i >> 13;                               // (dir<<1)|b
    const int p   = i & (NPTS - 1);
    const int dir = set >> 1, b = set & 1;
    const float* src = (dir ? pc1 : pc2) + ((size_t)b * NPTS + p) * 3;
    float* dst = soa + (size_t)set * 3 * NPTS;
    dst[p]            = src[0];
    dst[NPTS + p]     = src[1];
    dst[2 * NPTS + p] = src[2];
}

__global__ __launch_bounds__(KTH, 5) void knn_kernel(
    const float* __restrict__ pc1, const float* __restrict__ pc2,
    const float* __restrict__ soa, int* __restrict__ knn_out)
{
    // per-query row of 96 floats: [0..47] survd, [48..95] survi (as int).
    // cols [0..63] double as the rank table before phase 2 (wave-local).
    __shared__ float sbuf[QPB][2 * BUFCAP];          // 24 KB
    __shared__ float sthr[QPB];
    __shared__ int   scnt[QPB];

    const int t   = threadIdx.x;
    const int q0  = blockIdx.x * QPB;
    const int dir = q0 >> 14;
    const int b   = (q0 >> 13) & 1;

    const float* __restrict__ pq = dir ? pc2 : pc1;
    const float* __restrict__ cxp = soa + (size_t)((dir << 1) | b) * 3 * NPTS;
    const float* __restrict__ cyp = cxp + NPTS;
    const float* __restrict__ czp = cxp + 2 * NPTS;

    if (t < QPB) scnt[t] = 0;
    __syncthreads();

    const int ch = t & (CHN - 1);      // chunk 0..31
    const int qg = t >> 5;             // query group 0..7 (8 queries each)
    const int n0 = q0 & (NPTS - 1);

    // q2 = -2*q ; |q|^2 dropped (constant per query)
    float q2x[GQ], q2y[GQ], q2z[GQ];
    #pragma unroll
    for (int g = 0; g < GQ; ++g) {
        const float* qp = pq + ((size_t)b * NPTS + n0 + qg * GQ + g) * 3;
        q2x[g] = -2.0f * qp[0];
        q2y[g] = -2.0f * qp[1];
        q2z[g] = -2.0f * qp[2];
    }

    // ---- phase 1: min-2 per (thread,query), branchless ---------------------
    float m1[GQ], m2[GQ];
    #pragma unroll
    for (int g = 0; g < GQ; ++g) { m1[g] = 3.0e38f; m2[g] = 3.0e38f; }

    #pragma unroll 2
    for (int j = 0; j < JP; ++j) {
        const int i0 = j * 64 + 2 * ch;
        const float2 cx = *(const float2*)&cxp[i0];
        const float2 cy = *(const float2*)&cyp[i0];
        const float2 cz = *(const float2*)&czp[i0];
        const float cn0 = fmaf(cx.x, cx.x, fmaf(cy.x, cy.x, cz.x * cz.x));
        const float cn1 = fmaf(cx.y, cx.y, fmaf(cy.y, cy.y, cz.y * cz.y));
        #pragma unroll
        for (int g = 0; g < GQ; ++g) {
            const float d0 = fmaf(q2x[g], cx.x,
                             fmaf(q2y[g], cy.x,
                             fmaf(q2z[g], cz.x, cn0)));
            m2[g] = fminf(m2[g], fmaxf(m1[g], d0));   // median3 keeps 2nd-min
            m1[g] = fminf(m1[g], d0);
            const float d1 = fmaf(q2x[g], cx.y,
                             fmaf(q2y[g], cy.y,
                             fmaf(q2z[g], cz.y, cn1)));
            m2[g] = fminf(m2[g], fmaxf(m1[g], d1));
            m1[g] = fminf(m1[g], d1);
        }
    }

    // ---- threshold: 17th-smallest of 64 collected, lt/eq count table ------
    #pragma unroll
    for (int g = 0; g < GQ; ++g) {
        const int row = qg * GQ + g;
        sbuf[row][2 * ch]     = m1[g];
        sbuf[row][2 * ch + 1] = m2[g];
    }
    __builtin_amdgcn_wave_barrier();   // table rows are wave-local

    #pragma unroll
    for (int g = 0; g < GQ; ++g) {
        const int row = qg * GQ + g;
        const float v1 = m1[g], v2 = m2[g];
        int lt1 = 0, eq1 = 0, lt2 = 0, eq2 = 0;
        #pragma unroll
        for (int c = 0; c < 2 * CHN; c += 2) {
            const float2 vp = *(const float2*)&sbuf[row][c];
            lt1 += (vp.x < v1) ? 1 : 0;  eq1 += (vp.x == v1) ? 1 : 0;
            lt1 += (vp.y < v1) ? 1 : 0;  eq1 += (vp.y == v1) ? 1 : 0;
            lt2 += (vp.x < v2) ? 1 : 0;  eq2 += (vp.x == v2) ? 1 : 0;
            lt2 += (vp.y < v2) ? 1 : 0;  eq2 += (vp.y == v2) ? 1 : 0;
        }
        // value of rank 16 (0-based): lt <= 16 < lt+eq. Multiple writers
        // (ties) all write identical bits — benign.
        if (lt1 <= 16 && lt1 + eq1 > 16) sthr[row] = v1;
        if (lt2 <= 16 && lt2 + eq2 > 16) sthr[row] = v2;
    }
    __builtin_amdgcn_wave_barrier();

    // ---- phase 2: collect survivors (identical d' arithmetic) --------------
    float tq[GQ];
    #pragma unroll
    for (int g = 0; g < GQ; ++g) tq[g] = sthr[qg * GQ + g];

    #pragma unroll 2
    for (int j = 0; j < JP; ++j) {
        const int i0 = j * 64 + 2 * ch;
        const float2 cx = *(const float2*)&cxp[i0];
        const float2 cy = *(const float2*)&cyp[i0];
        const float2 cz = *(const float2*)&czp[i0];
        const float cn0 = fmaf(cx.x, cx.x, fmaf(cy.x, cy.x, cz.x * cz.x));
        const float cn1 = fmaf(cx.y, cx.y, fmaf(cy.y, cy.y, cz.y * cz.y));
        #pragma unroll
        for (int g = 0; g < GQ; ++g) {
            const float d0 = fmaf(q2x[g], cx.x,
                             fmaf(q2y[g], cy.x,
                             fmaf(q2z[g], cz.x, cn0)));
            if (d0 <= tq[g]) {
                const int q = qg * GQ + g;
                const int pos = atomicAdd(&scnt[q], 1);
                if (pos < BUFCAP) {
                    sbuf[q][pos] = d0;
                    ((int*)&sbuf[q][BUFCAP])[pos] = i0;
                }
            }
            const float d1 = fmaf(q2x[g], cx.y,
                             fmaf(q2y[g], cy.y,
                             fmaf(q2z[g], cz.y, cn1)));
            if (d1 <= tq[g]) {
                const int q = qg * GQ + g;
                const int pos = atomicAdd(&scnt[q], 1);
                if (pos < BUFCAP) {
                    sbuf[q][pos] = d1;
                    ((int*)&sbuf[q][BUFCAP])[pos] = i0 + 1;
                }
            }
        }
    }
    __syncthreads();

    // ---- phase 3: exact top-17 of survivors + fp64 refine ------------------
    if (t < QPB) {
        const int nc = min(scnt[t], BUFCAP);

        float dist[NSLOT];   // sorted descending by (d, idx); dist[0] = worst
        int   ind[NSLOT];
        #pragma unroll
        for (int i = 0; i < NSLOT; ++i) { dist[i] = 3.0e38f; ind[i] = 0x7fffffff; }

        for (int s = 0; s < nc; ++s) {
            const float d  = sbuf[t][s];
            const int   id = ((int*)&sbuf[t][BUFCAP])[s];
            const bool better0 = (d < dist[0]) || (d == dist[0] && id < ind[0]);
            if (better0) {
                bool cprev = true;
                #pragma unroll
                for (int i = 0; i < NSLOT - 1; ++i) {
                    const bool ci = (d < dist[i + 1]) ||
                                    (d == dist[i + 1] && id < ind[i + 1]);
                    const float nv = ci ? dist[i + 1] : (cprev ? d  : dist[i]);
                    const int   ni = ci ? ind[i + 1]  : (cprev ? id : ind[i]);
                    dist[i] = nv; ind[i] = ni;
                    cprev = ci;
                }
                if (cprev) { dist[NSLOT - 1] = d; ind[NSLOT - 1] = id; }
            }
        }

        const float* qpp = pq + ((size_t)b * NPTS + n0 + t) * 3;
        const double dqx = (double)qpp[0], dqy = (double)qpp[1], dqz = (double)qpp[2];
        double dd[NSLOT];
        #pragma unroll
        for (int i = 0; i < NSLOT; ++i) {
            const int id = ind[i];
            const double dx = (double)cxp[id] - dqx;
            const double dy = (double)cyp[id] - dqy;
            const double dz = (double)czp[id] - dqz;
            dd[i] = dx * dx + dy * dy + dz * dz;
        }
        int worst = 0; double wd = dd[0];
        #pragma unroll
        for (int i = 1; i < NSLOT; ++i) { if (dd[i] > wd) { wd = dd[i]; worst = i; } }

        int* outp = knn_out + (size_t)(q0 + t) * KNNK;
        int slot = 0;
        #pragma unroll
        for (int i = 0; i < NSLOT; ++i) {
            if (i != worst) outp[slot++] = ind[i];
        }
    }
}

// ---------------------------------------------------------------------------
// Kernel 2: feature MLP via bf16x3-split MFMA.
// Block = 256 thr (4 waves) x FP=4 points. Wave w owns N-tile w (out-channels
// 16w..16w+15); its B-fragments (hi+lo, both layers) live in registers.
// Activations pass between layers as LDS u32 = (bf16hi<<16 | bf16lo),
// row stride 68 (2-way bank aliasing only = free).
// ---------------------------------------------------------------------------
#define FP 4

__device__ __forceinline__ unsigned int packhl(float f) {
    const unsigned int u = __float_as_uint(f);
    const unsigned int h = u & 0xffff0000u;
    const float lf = f - __uint_as_float(h);
    return h | (__float_as_uint(lf) >> 16);
}

__device__ __forceinline__ void build_b(const float* __restrict__ wrow,
                                        bf16x8* hi, bf16x8* lo) {
    union { unsigned int u[4]; bf16x8 v; } H, L;
    #pragma unroll
    for (int r = 0; r < 4; ++r) {
        const float f0 = wrow[2 * r], f1 = wrow[2 * r + 1];
        const unsigned int h0 = __float_as_uint(f0) & 0xffff0000u;
        const unsigned int h1 = __float_as_uint(f1) & 0xffff0000u;
        const float l0 = f0 - __uint_as_float(h0);
        const float l1 = f1 - __uint_as_float(h1);
        H.u[r] = h1 | (h0 >> 16);
        L.u[r] = (__float_as_uint(l1) & 0xffff0000u) | (__float_as_uint(l0) >> 16);
    }
    *hi = H.v; *lo = L.v;
}

__device__ __forceinline__ void unpack_a(const unsigned int* __restrict__ Tu,
                                         bf16x8* hi, bf16x8* lo) {
    union { unsigned int u[4]; bf16x8 v; } H, L;
    #pragma unroll
    for (int r = 0; r < 4; ++r) {
        const unsigned int a = Tu[2 * r + 1], bb = Tu[2 * r];
        H.u[r] = __builtin_amdgcn_perm(a, bb, 0x07060302u);  // [a.hi16 : b.hi16]
        L.u[r] = __builtin_amdgcn_perm(a, bb, 0x05040100u);  // [a.lo16 : b.lo16]
    }
    *hi = H.v; *lo = L.v;
}

__device__ __forceinline__ f32x4 mfma3(f32x4 acc, bf16x8 ah, bf16x8 al,
                                       bf16x8 bh, bf16x8 bl) {
    acc = __builtin_amdgcn_mfma_f32_16x16x32_bf16(ah, bl, acc, 0, 0, 0);
    acc = __builtin_amdgcn_mfma_f32_16x16x32_bf16(al, bh, acc, 0, 0, 0);
    acc = __builtin_amdgcn_mfma_f32_16x16x32_bf16(ah, bh, acc, 0, 0, 0);
    return acc;
}

__global__ __launch_bounds__(256, 4) void feat_kernel(
    const float* __restrict__ pc1, const float* __restrict__ pc2,
    const float* __restrict__ feat1, const float* __restrict__ feat2,
    const float* __restrict__ pos_w, const float* __restrict__ pos_b,
    const float* __restrict__ w0, const float* __restrict__ b0,
    const float* __restrict__ w1, const float* __restrict__ b1,
    const float* __restrict__ t1w, const float* __restrict__ t1b,
    const float* __restrict__ t2w, const float* __restrict__ t2b,
    const int* __restrict__ knn, float* __restrict__ out)
{
    __shared__ unsigned int T0[FP][16][68];   // 17.4 KB packed activations
    __shared__ unsigned int T1[FP][16][68];   // 17.4 KB
    __shared__ float sm[FP][64];              // 1 KB pooled features

    const int t    = threadIdx.x;
    const int w    = t >> 6;          // wave = N-tile index 0..3
    const int lane = t & 63;
    const int m    = lane & 15;       // A-row (neighbor) / C-col (channel)
    const int quad = lane >> 4;

    const int p0  = blockIdx.x * FP;
    const int dir = p0 >> 14, bt = (p0 >> 13) & 1;
    const int n0  = p0 & (NPTS - 1);

    const float* __restrict__ pqd = dir ? pc2 : pc1;
    const float* __restrict__ pcd = dir ? pc1 : pc2;
    const float* __restrict__ fqd = dir ? feat2 : feat1;
    const float* __restrict__ fcd = dir ? feat1 : feat2;

    // ---- register-resident B-fragments: B[k][n] = W[n_glob][k] -------------
    const int ocol = w * 16 + m;               // this lane's output channel
    bf16x8 Bh[2][2], Bl[2][2];                 // [layer][ktile]
    #pragma unroll
    for (int kt = 0; kt < 2; ++kt) {
        build_b(&w0[(size_t)ocol * 64 + kt * 32 + quad * 8], &Bh[0][kt], &Bl[0][kt]);
        build_b(&w1[(size_t)ocol * 64 + kt * 32 + quad * 8], &Bh[1][kt], &Bl[1][kt]);
    }
    const float bias1 = b0[ocol];
    const float bias2 = b1[ocol];

    // ---- init-stage per-lane constants: channels cg0..cg0+3 ----------------
    const int cg0 = w * 16 + quad * 4;
    float pbc[4], pwx[4], pwy[4], pwz[4];
    #pragma unroll
    for (int i = 0; i < 4; ++i) {
        pbc[i] = pos_b[cg0 + i];
        pwx[i] = pos_w[(cg0 + i) * 3 + 0];
        pwy[i] = pos_w[(cg0 + i) * 3 + 1];
        pwz[i] = pos_w[(cg0 + i) * 3 + 2];
    }

    // ---- stage A: initial layer -> T0 (packed) -----------------------------
    #pragma unroll
    for (int pt = 0; pt < FP; ++pt) {
        const int p = p0 + pt, n = n0 + pt;
        const int id = knn[(size_t)p * KNNK + m];
        const float* qp  = pqd + ((size_t)bt * NPTS + n) * 3;
        const float* nbp = pcd + ((size_t)bt * NPTS + id) * 3;
        const float dx = nbp[0] - qp[0];
        const float dy = nbp[1] - qp[1];
        const float dz = nbp[2] - qp[2];
        const float4 gf = *(const float4*)&fcd[((size_t)bt * NPTS + id) * 64 + cg0];
        const float4 fq = *(const float4*)&fqd[((size_t)bt * NPTS + n) * 64 + cg0];
        const float gfa[4] = {gf.x, gf.y, gf.z, gf.w};
        const float fqa[4] = {fq.x, fq.y, fq.z, fq.w};
        uint4 U;
        unsigned int* Up = (unsigned int*)&U;
        #pragma unroll
        for (int i = 0; i < 4; ++i) {
            float v = gfa[i] + fqa[i] + pbc[i];
            v = fmaf(dx, pwx[i], v);
            v = fmaf(dy, pwy[i], v);
            v = fmaf(dz, pwz[i], v);
            v = fmaxf(v, LEAKY * v);
            Up[i] = packhl(v);
        }
        *(uint4*)&T0[pt][m][cg0] = U;
    }
    __syncthreads();

    // ---- stage B: layer 1 (MFMA) -> T1 -------------------------------------
    #pragma unroll
    for (int pt = 0; pt < FP; ++pt) {
        unsigned int Tu[8];
        bf16x8 Ah, Al;
        f32x4 acc = {0.f, 0.f, 0.f, 0.f};
        #pragma unroll
        for (int kt = 0; kt < 2; ++kt) {
            *(uint4*)&Tu[0] = *(const uint4*)&T0[pt][m][kt * 32 + quad * 8];
            *(uint4*)&Tu[4] = *(const uint4*)&T0[pt][m][kt * 32 + quad * 8 + 4];
            unpack_a(Tu, &Ah, &Al);
            acc = mfma3(acc, Ah, Al, Bh[0][kt], Bl[0][kt]);
        }
        #pragma unroll
        for (int r = 0; r < 4; ++r) {
            float v = acc[r] + bias1;
            v = fmaxf(v, LEAKY * v);
            T1[pt][quad * 4 + r][ocol] = packhl(v);
        }
    }
    __syncthreads();

    // ---- stage C: layer 2 (MFMA) + max-pool -> sm --------------------------
    #pragma unroll
    for (int pt = 0; pt < FP; ++pt) {
        unsigned int Tu[8];
        bf16x8 Ah, Al;
        f32x4 acc = {0.f, 0.f, 0.f, 0.f};
        #pragma unroll
        for (int kt = 0; kt < 2; ++kt) {
            *(uint4*)&Tu[0] = *(const uint4*)&T1[pt][m][kt * 32 + quad * 8];
            *(uint4*)&Tu[4] = *(const uint4*)&T1[pt][m][kt * 32 + quad * 8 + 4];
            unpack_a(Tu, &Ah, &Al);
            acc = mfma3(acc, Ah, Al, Bh[1][kt], Bl[1][kt]);
        }
        float mx = -3.0e38f;
        #pragma unroll
        for (int r = 0; r < 4; ++r) {
            float v = acc[r] + bias2;
            v = fmaxf(v, LEAKY * v);
            mx = fmaxf(mx, v);
        }
        mx = fmaxf(mx, __shfl_xor(mx, 16));
        mx = fmaxf(mx, __shfl_xor(mx, 32));
        if (quad == 0) sm[pt][ocol] = mx;
    }
    __syncthreads();

    // ---- stage D: final 64->128 linear -------------------------------------
    {
        const float* __restrict__ tw = dir ? t2w : t1w;
        const float* __restrict__ tb = dir ? t2b : t1b;
        const int o  = t & 127;
        const int pg = t >> 7;                 // 2 point-pairs
        const int pa = pg * 2, pb = pg * 2 + 1;
        float acc0 = tb[o], acc1 = acc0;
        #pragma unroll
        for (int cc = 0; cc < 64; cc += 4) {
            const float4 wq = *(const float4*)&tw[(size_t)o * 64 + cc];
            const float4 a0 = *(const float4*)&sm[pa][cc];
            const float4 a1 = *(const float4*)&sm[pb][cc];
            acc0 = fmaf(a0.x, wq.x, acc0); acc0 = fmaf(a0.y, wq.y, acc0);
            acc0 = fmaf(a0.z, wq.z, acc0); acc0 = fmaf(a0.w, wq.w, acc0);
            acc1 = fmaf(a1.x, wq.x, acc1); acc1 = fmaf(a1.y, wq.y, acc1);
            acc1 = fmaf(a1.z, wq.z, acc1); acc1 = fmaf(a1.w, wq.w, acc1);
        }
        float* op = out + (size_t)dir * (2 * NPTS * 128);
        op[((size_t)bt * NPTS + n0 + pa) * 128 + o] = acc0;
        op[((size_t)bt * NPTS + n0 + pb) * 128 + o] = acc1;
    }
}

// ---------------------------------------------------------------------------
extern "C" void kernel_launch(void* const* d_in, const int* in_sizes, int n_in,
                              void* d_out, int out_size, void* d_ws, size_t ws_size,
                              hipStream_t stream)
{
    const float* pc1   = (const float*)d_in[0];
    const float* pc2   = (const float*)d_in[1];
    const float* feat1 = (const float*)d_in[2];
    const float* feat2 = (const float*)d_in[3];
    const float* pos_w = (const float*)d_in[4];
    const float* pos_b = (const float*)d_in[5];
    const float* w0    = (const float*)d_in[6];
    const float* b0    = (const float*)d_in[7];
    const float* w1    = (const float*)d_in[8];
    const float* b1    = (const float*)d_in[9];
    const float* t1w   = (const float*)d_in[10];
    const float* t1b   = (const float*)d_in[11];
    const float* t2w   = (const float*)d_in[12];
    const float* t2b   = (const float*)d_in[13];

    int*   knn = (int*)d_ws;          // 32768 * 16 ints = 2 MB scratch
    float* out = (float*)d_out;

    // candidate SoA scratch: 4 sets x 3 coords x 8192 = 384 KB.
    // Prefer workspace tail; fall back to d_out (fully overwritten later by
    // feat_kernel, stream-ordered, so this is hazard-free).
    const size_t knn_bytes = (size_t)32768 * KNNK * sizeof(int);
    const size_t soa_bytes = (size_t)4 * 3 * NPTS * sizeof(float);
    float* soa;
    if (ws_size >= knn_bytes + soa_bytes)
        soa = (float*)((char*)d_ws + knn_bytes);
    else
        soa = (float*)d_out;

    hipLaunchKernelGGL(prep_kernel, dim3(32768 / 256), dim3(256), 0, stream,
                       pc1, pc2, soa);
    hipLaunchKernelGGL(knn_kernel, dim3(32768 / QPB), dim3(KTH), 0, stream,
                       pc1, pc2, soa, knn);
    hipLaunchKernelGGL(feat_kernel, dim3(32768 / FP), dim3(256), 0, stream,
                       pc1, pc2, feat1, feat2, pos_w, pos_b,
                       w0, b0, w1, b1, t1w, t1b, t2w, t2b, knn, out);
}

// Round 3
// 330.568 us; speedup vs baseline: 1.3977x; 1.3977x over previous
//
#include <hip/hip_runtime.h>

#define NPTS 8192
#define KNNK 16
#define NSLOT 17          // keep 17, fp64-refine drops the worst -> robust 16-set
#define LEAKY 0.1f

typedef short bf16x8 __attribute__((ext_vector_type(8)));
typedef float f32x4  __attribute__((ext_vector_type(4)));

// ---- knn config ----
#define KTH   1024             // threads/block (16 waves) -- occupancy fix
#define QPB   128              // queries per block -> grid 256
#define CHN   32               // chunks (threads) per query
#define GQ    4                // queries per thread
#define JP    (NPTS / 64)      // 128 iters, 2 adjacent candidates per thread/iter
#define BUFCAP 48              // survivor buffer per query

// ---------------------------------------------------------------------------
// R7: occupancy was GRID-capped all along (R6 proved it: LDS 25KB + VGPR 48
// still showed 21.5% = 2048 waves / 8192 slots). Fix by launching more waves,
// not by shrinking LDS: 1024-thr blocks (16 waves/CU = 4/SIMD = 50% ceiling),
// QPB=128, GQ=4. Candidates return to LDS (R6's L2 reads added ~200cy latency
// with no waves to hide it -> 271us regression; reverted). Distance math,
// rank-17 threshold (32 chunks x min-2 = 64-entry table), survivor buffer,
// fp64 refine all unchanged from R5.
// ---------------------------------------------------------------------------
__global__ __launch_bounds__(KTH, 4) void knn_kernel(
    const float* __restrict__ pc1, const float* __restrict__ pc2,
    int* __restrict__ knn_out)
{
    __shared__ float sx[NPTS], sy[NPTS], sz[NPTS];   // 96 KB candidate SoA
    // per-query row of 96 floats: [0..47] survd, [48..95] survi (as int).
    // cols [0..63] double as the rank table before phase 2 (wave-local).
    __shared__ float sbuf[QPB][2 * BUFCAP];          // 48 KB
    __shared__ float sthr[QPB];
    __shared__ int   scnt[QPB];

    const int t   = threadIdx.x;
    const int q0  = blockIdx.x * QPB;
    const int dir = q0 >> 14;
    const int b   = (q0 >> 13) & 1;

    const float* __restrict__ pq    = dir ? pc2 : pc1;
    const float* __restrict__ pcand = dir ? pc1 : pc2;

    const float* src = pcand + (size_t)b * NPTS * 3;
    for (int i = t; i < NPTS; i += KTH) {
        sx[i] = src[3 * i];
        sy[i] = src[3 * i + 1];
        sz[i] = src[3 * i + 2];
    }
    if (t < QPB) scnt[t] = 0;
    __syncthreads();

    const int ch = t & (CHN - 1);      // chunk 0..31
    const int qg = t >> 5;             // query group 0..31 (4 queries each)
    const int n0 = q0 & (NPTS - 1);

    // q2 = -2*q ; |q|^2 dropped (constant per query)
    float q2x[GQ], q2y[GQ], q2z[GQ];
    #pragma unroll
    for (int g = 0; g < GQ; ++g) {
        const float* qp = pq + ((size_t)b * NPTS + n0 + qg * GQ + g) * 3;
        q2x[g] = -2.0f * qp[0];
        q2y[g] = -2.0f * qp[1];
        q2z[g] = -2.0f * qp[2];
    }

    // ---- phase 1: min-2 per (thread,query), branchless ---------------------
    float m1[GQ], m2[GQ];
    #pragma unroll
    for (int g = 0; g < GQ; ++g) { m1[g] = 3.0e38f; m2[g] = 3.0e38f; }

    #pragma unroll 2
    for (int j = 0; j < JP; ++j) {
        const int i0 = j * 64 + 2 * ch;
        const float2 cx = *(const float2*)&sx[i0];
        const float2 cy = *(const float2*)&sy[i0];
        const float2 cz = *(const float2*)&sz[i0];
        const float cn0 = fmaf(cx.x, cx.x, fmaf(cy.x, cy.x, cz.x * cz.x));
        const float cn1 = fmaf(cx.y, cx.y, fmaf(cy.y, cy.y, cz.y * cz.y));
        #pragma unroll
        for (int g = 0; g < GQ; ++g) {
            const float d0 = fmaf(q2x[g], cx.x,
                             fmaf(q2y[g], cy.x,
                             fmaf(q2z[g], cz.x, cn0)));
            m2[g] = fminf(m2[g], fmaxf(m1[g], d0));   // median3 keeps 2nd-min
            m1[g] = fminf(m1[g], d0);
            const float d1 = fmaf(q2x[g], cx.y,
                             fmaf(q2y[g], cy.y,
                             fmaf(q2z[g], cz.y, cn1)));
            m2[g] = fminf(m2[g], fmaxf(m1[g], d1));
            m1[g] = fminf(m1[g], d1);
        }
    }

    // ---- threshold: 17th-smallest of 64 collected, lt/eq count table ------
    #pragma unroll
    for (int g = 0; g < GQ; ++g) {
        const int row = qg * GQ + g;
        sbuf[row][2 * ch]     = m1[g];
        sbuf[row][2 * ch + 1] = m2[g];
    }
    __builtin_amdgcn_wave_barrier();   // table rows are wave-local (32-thr group)

    #pragma unroll
    for (int g = 0; g < GQ; ++g) {
        const int row = qg * GQ + g;
        const float v1 = m1[g], v2 = m2[g];
        int lt1 = 0, eq1 = 0, lt2 = 0, eq2 = 0;
        #pragma unroll
        for (int c = 0; c < 2 * CHN; c += 2) {
            const float2 vp = *(const float2*)&sbuf[row][c];
            lt1 += (vp.x < v1) ? 1 : 0;  eq1 += (vp.x == v1) ? 1 : 0;
            lt1 += (vp.y < v1) ? 1 : 0;  eq1 += (vp.y == v1) ? 1 : 0;
            lt2 += (vp.x < v2) ? 1 : 0;  eq2 += (vp.x == v2) ? 1 : 0;
            lt2 += (vp.y < v2) ? 1 : 0;  eq2 += (vp.y == v2) ? 1 : 0;
        }
        // value of rank 16 (0-based): lt <= 16 < lt+eq. Multiple writers
        // (ties) all write identical bits — benign.
        if (lt1 <= 16 && lt1 + eq1 > 16) sthr[row] = v1;
        if (lt2 <= 16 && lt2 + eq2 > 16) sthr[row] = v2;
    }
    __builtin_amdgcn_wave_barrier();

    // ---- phase 2: collect survivors (identical d' arithmetic) --------------
    float tq[GQ];
    #pragma unroll
    for (int g = 0; g < GQ; ++g) tq[g] = sthr[qg * GQ + g];

    #pragma unroll 2
    for (int j = 0; j < JP; ++j) {
        const int i0 = j * 64 + 2 * ch;
        const float2 cx = *(const float2*)&sx[i0];
        const float2 cy = *(const float2*)&sy[i0];
        const float2 cz = *(const float2*)&sz[i0];
        const float cn0 = fmaf(cx.x, cx.x, fmaf(cy.x, cy.x, cz.x * cz.x));
        const float cn1 = fmaf(cx.y, cx.y, fmaf(cy.y, cy.y, cz.y * cz.y));
        #pragma unroll
        for (int g = 0; g < GQ; ++g) {
            const float d0 = fmaf(q2x[g], cx.x,
                             fmaf(q2y[g], cy.x,
                             fmaf(q2z[g], cz.x, cn0)));
            if (d0 <= tq[g]) {
                const int q = qg * GQ + g;
                const int pos = atomicAdd(&scnt[q], 1);
                if (pos < BUFCAP) {
                    sbuf[q][pos] = d0;
                    ((int*)&sbuf[q][BUFCAP])[pos] = i0;
                }
            }
            const float d1 = fmaf(q2x[g], cx.y,
                             fmaf(q2y[g], cy.y,
                             fmaf(q2z[g], cz.y, cn1)));
            if (d1 <= tq[g]) {
                const int q = qg * GQ + g;
                const int pos = atomicAdd(&scnt[q], 1);
                if (pos < BUFCAP) {
                    sbuf[q][pos] = d1;
                    ((int*)&sbuf[q][BUFCAP])[pos] = i0 + 1;
                }
            }
        }
    }
    __syncthreads();

    // ---- phase 3: exact top-17 of survivors + fp64 refine ------------------
    if (t < QPB) {
        const int nc = min(scnt[t], BUFCAP);

        float dist[NSLOT];   // sorted descending by (d, idx); dist[0] = worst
        int   ind[NSLOT];
        #pragma unroll
        for (int i = 0; i < NSLOT; ++i) { dist[i] = 3.0e38f; ind[i] = 0x7fffffff; }

        for (int s = 0; s < nc; ++s) {
            const float d  = sbuf[t][s];
            const int   id = ((int*)&sbuf[t][BUFCAP])[s];
            const bool better0 = (d < dist[0]) || (d == dist[0] && id < ind[0]);
            if (better0) {
                bool cprev = true;
                #pragma unroll
                for (int i = 0; i < NSLOT - 1; ++i) {
                    const bool ci = (d < dist[i + 1]) ||
                                    (d == dist[i + 1] && id < ind[i + 1]);
                    const float nv = ci ? dist[i + 1] : (cprev ? d  : dist[i]);
                    const int   ni = ci ? ind[i + 1]  : (cprev ? id : ind[i]);
                    dist[i] = nv; ind[i] = ni;
                    cprev = ci;
                }
                if (cprev) { dist[NSLOT - 1] = d; ind[NSLOT - 1] = id; }
            }
        }

        const float* qpp = pq + ((size_t)b * NPTS + n0 + t) * 3;
        const double dqx = (double)qpp[0], dqy = (double)qpp[1], dqz = (double)qpp[2];
        double dd[NSLOT];
        #pragma unroll
        for (int i = 0; i < NSLOT; ++i) {
            const int id = ind[i];
            const double dx = (double)sx[id] - dqx;
            const double dy = (double)sy[id] - dqy;
            const double dz = (double)sz[id] - dqz;
            dd[i] = dx * dx + dy * dy + dz * dz;
        }
        int worst = 0; double wd = dd[0];
        #pragma unroll
        for (int i = 1; i < NSLOT; ++i) { if (dd[i] > wd) { wd = dd[i]; worst = i; } }

        int* outp = knn_out + (size_t)(q0 + t) * KNNK;
        int slot = 0;
        #pragma unroll
        for (int i = 0; i < NSLOT; ++i) {
            if (i != worst) outp[slot++] = ind[i];
        }
    }
}

// ---------------------------------------------------------------------------
// Kernel 2: feature MLP via bf16x3-split MFMA.
// Block = 256 thr (4 waves) x FP=4 points. Wave w owns N-tile w (out-channels
// 16w..16w+15); its B-fragments (hi+lo, both layers) live in registers.
// Activations pass between layers as LDS u32 = (bf16hi<<16 | bf16lo),
// row stride 68 (2-way bank aliasing only = free).
// ---------------------------------------------------------------------------
#define FP 4

__device__ __forceinline__ unsigned int packhl(float f) {
    const unsigned int u = __float_as_uint(f);
    const unsigned int h = u & 0xffff0000u;
    const float lf = f - __uint_as_float(h);
    return h | (__float_as_uint(lf) >> 16);
}

__device__ __forceinline__ void build_b(const float* __restrict__ wrow,
                                        bf16x8* hi, bf16x8* lo) {
    union { unsigned int u[4]; bf16x8 v; } H, L;
    #pragma unroll
    for (int r = 0; r < 4; ++r) {
        const float f0 = wrow[2 * r], f1 = wrow[2 * r + 1];
        const unsigned int h0 = __float_as_uint(f0) & 0xffff0000u;
        const unsigned int h1 = __float_as_uint(f1) & 0xffff0000u;
        const float l0 = f0 - __uint_as_float(h0);
        const float l1 = f1 - __uint_as_float(h1);
        H.u[r] = h1 | (h0 >> 16);
        L.u[r] = (__float_as_uint(l1) & 0xffff0000u) | (__float_as_uint(l0) >> 16);
    }
    *hi = H.v; *lo = L.v;
}

__device__ __forceinline__ void unpack_a(const unsigned int* __restrict__ Tu,
                                         bf16x8* hi, bf16x8* lo) {
    union { unsigned int u[4]; bf16x8 v; } H, L;
    #pragma unroll
    for (int r = 0; r < 4; ++r) {
        const unsigned int a = Tu[2 * r + 1], bb = Tu[2 * r];
        H.u[r] = __builtin_amdgcn_perm(a, bb, 0x07060302u);  // [a.hi16 : b.hi16]
        L.u[r] = __builtin_amdgcn_perm(a, bb, 0x05040100u);  // [a.lo16 : b.lo16]
    }
    *hi = H.v; *lo = L.v;
}

__device__ __forceinline__ f32x4 mfma3(f32x4 acc, bf16x8 ah, bf16x8 al,
                                       bf16x8 bh, bf16x8 bl) {
    acc = __builtin_amdgcn_mfma_f32_16x16x32_bf16(ah, bl, acc, 0, 0, 0);
    acc = __builtin_amdgcn_mfma_f32_16x16x32_bf16(al, bh, acc, 0, 0, 0);
    acc = __builtin_amdgcn_mfma_f32_16x16x32_bf16(ah, bh, acc, 0, 0, 0);
    return acc;
}

__global__ __launch_bounds__(256, 4) void feat_kernel(
    const float* __restrict__ pc1, const float* __restrict__ pc2,
    const float* __restrict__ feat1, const float* __restrict__ feat2,
    const float* __restrict__ pos_w, const float* __restrict__ pos_b,
    const float* __restrict__ w0, const float* __restrict__ b0,
    const float* __restrict__ w1, const float* __restrict__ b1,
    const float* __restrict__ t1w, const float* __restrict__ t1b,
    const float* __restrict__ t2w, const float* __restrict__ t2b,
    const int* __restrict__ knn, float* __restrict__ out)
{
    __shared__ unsigned int T0[FP][16][68];   // 17.4 KB packed activations
    __shared__ unsigned int T1[FP][16][68];   // 17.4 KB
    __shared__ float sm[FP][64];              // 1 KB pooled features

    const int t    = threadIdx.x;
    const int w    = t >> 6;          // wave = N-tile index 0..3
    const int lane = t & 63;
    const int m    = lane & 15;       // A-row (neighbor) / C-col (channel)
    const int quad = lane >> 4;

    const int p0  = blockIdx.x * FP;
    const int dir = p0 >> 14, bt = (p0 >> 13) & 1;
    const int n0  = p0 & (NPTS - 1);

    const float* __restrict__ pqd = dir ? pc2 : pc1;
    const float* __restrict__ pcd = dir ? pc1 : pc2;
    const float* __restrict__ fqd = dir ? feat2 : feat1;
    const float* __restrict__ fcd = dir ? feat1 : feat2;

    // ---- register-resident B-fragments: B[k][n] = W[n_glob][k] -------------
    const int ocol = w * 16 + m;               // this lane's output channel
    bf16x8 Bh[2][2], Bl[2][2];                 // [layer][ktile]
    #pragma unroll
    for (int kt = 0; kt < 2; ++kt) {
        build_b(&w0[(size_t)ocol * 64 + kt * 32 + quad * 8], &Bh[0][kt], &Bl[0][kt]);
        build_b(&w1[(size_t)ocol * 64 + kt * 32 + quad * 8], &Bh[1][kt], &Bl[1][kt]);
    }
    const float bias1 = b0[ocol];
    const float bias2 = b1[ocol];

    // ---- init-stage per-lane constants: channels cg0..cg0+3 ----------------
    const int cg0 = w * 16 + quad * 4;
    float pbc[4], pwx[4], pwy[4], pwz[4];
    #pragma unroll
    for (int i = 0; i < 4; ++i) {
        pbc[i] = pos_b[cg0 + i];
        pwx[i] = pos_w[(cg0 + i) * 3 + 0];
        pwy[i] = pos_w[(cg0 + i) * 3 + 1];
        pwz[i] = pos_w[(cg0 + i) * 3 + 2];
    }

    // ---- stage A: initial layer -> T0 (packed) -----------------------------
    #pragma unroll
    for (int pt = 0; pt < FP; ++pt) {
        const int p = p0 + pt, n = n0 + pt;
        const int id = knn[(size_t)p * KNNK + m];
        const float* qp  = pqd + ((size_t)bt * NPTS + n) * 3;
        const float* nbp = pcd + ((size_t)bt * NPTS + id) * 3;
        const float dx = nbp[0] - qp[0];
        const float dy = nbp[1] - qp[1];
        const float dz = nbp[2] - qp[2];
        const float4 gf = *(const float4*)&fcd[((size_t)bt * NPTS + id) * 64 + cg0];
        const float4 fq = *(const float4*)&fqd[((size_t)bt * NPTS + n) * 64 + cg0];
        const float gfa[4] = {gf.x, gf.y, gf.z, gf.w};
        const float fqa[4] = {fq.x, fq.y, fq.z, fq.w};
        uint4 U;
        unsigned int* Up = (unsigned int*)&U;
        #pragma unroll
        for (int i = 0; i < 4; ++i) {
            float v = gfa[i] + fqa[i] + pbc[i];
            v = fmaf(dx, pwx[i], v);
            v = fmaf(dy, pwy[i], v);
            v = fmaf(dz, pwz[i], v);
            v = fmaxf(v, LEAKY * v);
            Up[i] = packhl(v);
        }
        *(uint4*)&T0[pt][m][cg0] = U;
    }
    __syncthreads();

    // ---- stage B: layer 1 (MFMA) -> T1 -------------------------------------
    #pragma unroll
    for (int pt = 0; pt < FP; ++pt) {
        unsigned int Tu[8];
        bf16x8 Ah, Al;
        f32x4 acc = {0.f, 0.f, 0.f, 0.f};
        #pragma unroll
        for (int kt = 0; kt < 2; ++kt) {
            *(uint4*)&Tu[0] = *(const uint4*)&T0[pt][m][kt * 32 + quad * 8];
            *(uint4*)&Tu[4] = *(const uint4*)&T0[pt][m][kt * 32 + quad * 8 + 4];
            unpack_a(Tu, &Ah, &Al);
            acc = mfma3(acc, Ah, Al, Bh[0][kt], Bl[0][kt]);
        }
        #pragma unroll
        for (int r = 0; r < 4; ++r) {
            float v = acc[r] + bias1;
            v = fmaxf(v, LEAKY * v);
            T1[pt][quad * 4 + r][ocol] = packhl(v);
        }
    }
    __syncthreads();

    // ---- stage C: layer 2 (MFMA) + max-pool -> sm --------------------------
    #pragma unroll
    for (int pt = 0; pt < FP; ++pt) {
        unsigned int Tu[8];
        bf16x8 Ah, Al;
        f32x4 acc = {0.f, 0.f, 0.f, 0.f};
        #pragma unroll
        for (int kt = 0; kt < 2; ++kt) {
            *(uint4*)&Tu[0] = *(const uint4*)&T1[pt][m][kt * 32 + quad * 8];
            *(uint4*)&Tu[4] = *(const uint4*)&T1[pt][m][kt * 32 + quad * 8 + 4];
            unpack_a(Tu, &Ah, &Al);
            acc = mfma3(acc, Ah, Al, Bh[1][kt], Bl[1][kt]);
        }
        float mx = -3.0e38f;
        #pragma unroll
        for (int r = 0; r < 4; ++r) {
            float v = acc[r] + bias2;
            v = fmaxf(v, LEAKY * v);
            mx = fmaxf(mx, v);
        }
        mx = fmaxf(mx, __shfl_xor(mx, 16));
        mx = fmaxf(mx, __shfl_xor(mx, 32));
        if (quad == 0) sm[pt][ocol] = mx;
    }
    __syncthreads();

    // ---- stage D: final 64->128 linear -------------------------------------
    {
        const float* __restrict__ tw = dir ? t2w : t1w;
        const float* __restrict__ tb = dir ? t2b : t1b;
        const int o  = t & 127;
        const int pg = t >> 7;                 // 2 point-pairs
        const int pa = pg * 2, pb = pg * 2 + 1;
        float acc0 = tb[o], acc1 = acc0;
        #pragma unroll
        for (int cc = 0; cc < 64; cc += 4) {
            const float4 wq = *(const float4*)&tw[(size_t)o * 64 + cc];
            const float4 a0 = *(const float4*)&sm[pa][cc];
            const float4 a1 = *(const float4*)&sm[pb][cc];
            acc0 = fmaf(a0.x, wq.x, acc0); acc0 = fmaf(a0.y, wq.y, acc0);
            acc0 = fmaf(a0.z, wq.z, acc0); acc0 = fmaf(a0.w, wq.w, acc0);
            acc1 = fmaf(a1.x, wq.x, acc1); acc1 = fmaf(a1.y, wq.y, acc1);
            acc1 = fmaf(a1.z, wq.z, acc1); acc1 = fmaf(a1.w, wq.w, acc1);
        }
        float* op = out + (size_t)dir * (2 * NPTS * 128);
        op[((size_t)bt * NPTS + n0 + pa) * 128 + o] = acc0;
        op[((size_t)bt * NPTS + n0 + pb) * 128 + o] = acc1;
    }
}

// ---------------------------------------------------------------------------
extern "C" void kernel_launch(void* const* d_in, const int* in_sizes, int n_in,
                              void* d_out, int out_size, void* d_ws, size_t ws_size,
                              hipStream_t stream)
{
    const float* pc1   = (const float*)d_in[0];
    const float* pc2   = (const float*)d_in[1];
    const float* feat1 = (const float*)d_in[2];
    const float* feat2 = (const float*)d_in[3];
    const float* pos_w = (const float*)d_in[4];
    const float* pos_b = (const float*)d_in[5];
    const float* w0    = (const float*)d_in[6];
    const float* b0    = (const float*)d_in[7];
    const float* w1    = (const float*)d_in[8];
    const float* b1    = (const float*)d_in[9];
    const float* t1w   = (const float*)d_in[10];
    const float* t1b   = (const float*)d_in[11];
    const float* t2w   = (const float*)d_in[12];
    const float* t2b   = (const float*)d_in[13];

    int*   knn = (int*)d_ws;          // 32768 * 16 ints = 2 MB scratch
    float* out = (float*)d_out;

    hipLaunchKernelGGL(knn_kernel, dim3(32768 / QPB), dim3(KTH), 0, stream,
                       pc1, pc2, knn);
    hipLaunchKernelGGL(feat_kernel, dim3(32768 / FP), dim3(256), 0, stream,
                       pc1, pc2, feat1, feat2, pos_w, pos_b,
                       w0, b0, w1, b1, t1w, t1b, t2w, t2b, knn, out);
}